// Round 1
// baseline (535.464 us; speedup 1.0000x reference)
//
#include <hip/hip_runtime.h>
#include <math.h>

#define NDEG 26

struct PhaseB {
  float Wl[128][64];     // 32768 B  W staged
  float Xt[128][32];     // 16384 B  X time-tile
  float XwT[32][68];     //  8704 B  (W^T X) tile, [t][d], padded row 68
  float msum8[128][8];   //  4096 B  row-sum partials
  float msum[128];       //   512 B
  float mw[64];          //   256 B
};
struct PhaseC {
  float M[64][68];       // 17408 B  (Y - c I)/h  (symmetric)
  float bufA[64][68];
  float bufB[64][68];
  float red[256][4];     //  4096 B  output reduction
};
union SmemU { PhaseB b; PhaseC c; };   // 62720 B max

__device__ __forceinline__ void fma4(float4& a, const float4& v, const float s) {
  a.x = fmaf(v.x, s, a.x);
  a.y = fmaf(v.y, s, a.y);
  a.z = fmaf(v.z, s, a.z);
  a.w = fmaf(v.w, s, a.w);
}

__global__ __launch_bounds__(256, 2) void spdnet_fused_kernel(
    const float* __restrict__ X,
    const float* __restrict__ W,
    const float* __restrict__ lin_w,
    const float* __restrict__ lin_b,
    float* __restrict__ out)
{
  __shared__ SmemU sm;
  const int b = blockIdx.x;
  const int t = threadIdx.x;
  const float* __restrict__ Xb = X + (size_t)b * 128000u;

  // ---- stage W [128][64] into LDS ----
  {
    float* wl = &sm.b.Wl[0][0];
#pragma unroll
    for (int u = 0; u < 8; ++u) {
      const int idx = (t + 256 * u) * 4;
      *(float4*)&wl[idx] = *(const float4*)&W[idx];
    }
  }

  const int r0  = t >> 3;          // load row base (0..31)
  const int c4  = (t & 7) << 2;    // load col within 32-tile
  const int i4  = (t & 15) << 2;   // output tile row base
  const int j4  = (t >> 4) << 2;   // output tile col base
  const int tc2 = (t >> 4) << 1;   // step-3 time-col pair

  float rs[4] = {0.f, 0.f, 0.f, 0.f};
  float4 yr[4];
#pragma unroll
  for (int u = 0; u < 4; ++u) yr[u] = make_float4(0.f, 0.f, 0.f, 0.f);

  // preload tile 0 to registers
  float4 pre[4];
#pragma unroll
  for (int u = 0; u < 4; ++u)
    pre[u] = *(const float4*)&Xb[(r0 + 32 * u) * 1000 + c4];

  // ---- K loop over time, tiles of 32 (last tile zero-padded: 1000 = 31*32+8) ----
  for (int it = 0; it < 32; ++it) {
    __syncthreads();
    // store preloaded tile; accumulate row sums (zeros are harmless)
#pragma unroll
    for (int u = 0; u < 4; ++u) {
      *(float4*)&sm.b.Xt[r0 + 32 * u][c4] = pre[u];
      rs[u] += pre[u].x + pre[u].y + pre[u].z + pre[u].w;
    }
    // prefetch next tile (hidden under compute below)
    if (it + 1 < 32) {
      const int tg = (it + 1) * 32 + c4;
      if (tg < 1000) {
#pragma unroll
        for (int u = 0; u < 4; ++u)
          pre[u] = *(const float4*)&Xb[(r0 + 32 * u) * 1000 + tg];
      } else {
#pragma unroll
        for (int u = 0; u < 4; ++u) pre[u] = make_float4(0.f, 0.f, 0.f, 0.f);
      }
    }
    __syncthreads();
    // step 3: XwT[tc][d] = sum_c Wl[c][d] * Xt[c][tc]   (each thread: 4d x 2tc)
    {
      float4 a0 = make_float4(0.f, 0.f, 0.f, 0.f);
      float4 a1 = make_float4(0.f, 0.f, 0.f, 0.f);
#pragma unroll 4
      for (int c = 0; c < 128; ++c) {
        const float4 w4 = *(const float4*)&sm.b.Wl[c][i4];
        const float  x0 = sm.b.Xt[c][tc2];
        const float  x1 = sm.b.Xt[c][tc2 + 1];
        fma4(a0, w4, x0);
        fma4(a1, w4, x1);
      }
      *(float4*)&sm.b.XwT[tc2][i4]     = a0;
      *(float4*)&sm.b.XwT[tc2 + 1][i4] = a1;
    }
    __syncthreads();
    // step 5: Yacc[i][j] += sum_t Xw[i][t]*Xw[j][t]  (each thread: 4x4 tile)
#pragma unroll 4
    for (int tt = 0; tt < 32; ++tt) {
      const float4 xi = *(const float4*)&sm.b.XwT[tt][i4];
      const float4 xj = *(const float4*)&sm.b.XwT[tt][j4];
      fma4(yr[0], xj, xi.x);
      fma4(yr[1], xj, xi.y);
      fma4(yr[2], xj, xi.z);
      fma4(yr[3], xj, xi.w);
    }
  }

  // ---- means: msum -> mw = W^T mean ----
  __syncthreads();
#pragma unroll
  for (int u = 0; u < 4; ++u) sm.b.msum8[r0 + 32 * u][t & 7] = rs[u];
  __syncthreads();
  if (t < 128) {
    float s = 0.f;
#pragma unroll
    for (int j = 0; j < 8; ++j) s += sm.b.msum8[t][j];
    sm.b.msum[t] = s;
  }
  __syncthreads();
  if (t < 64) {
    float s = 0.f;
    for (int c = 0; c < 128; ++c) s = fmaf(sm.b.Wl[c][t], sm.b.msum[c], s);
    sm.b.mw[t] = s * 1.0e-3f;
  }
  __syncthreads();
  float mwi[4];
#pragma unroll
  for (int u = 0; u < 4; ++u) mwi[u] = sm.b.mw[i4 + u];
  const float4 mwj = *(const float4*)&sm.b.mw[j4];
  __syncthreads();  // all reads of Wl/mw done; LDS union repurposed below

  // ---- Chebyshev matrix-log setup (closed-form coefficients) ----
  // log(c + h*t) = log(gam) - 2*sum_{k>=1} (rho^k/k) T_k(t),  interval [0.25, 2.0]
  const float cc   = 1.125f;
  const float hh   = 0.875f;
  const float invh = 1.0f / hh;
  const float uu   = hh / cc;
  const float rho  = (sqrtf(1.0f - uu * uu) - 1.0f) / uu;   // ~ -0.47759
  const float gam  = cc / (1.0f + rho * rho);
  const float a0c  = logf(gam);
  const float a1c  = -2.0f * rho;
  const float invT = 1.0e-3f;

  float4 zz[4], tp[4], tcu[4];
#pragma unroll
  for (int u = 0; u < 4; ++u) {
    const int row = i4 + u;
    float4 m;
    m.x = (yr[u].x * invT - mwi[u] * mwj.x - ((row == j4 + 0) ? cc : 0.f)) * invh;
    m.y = (yr[u].y * invT - mwi[u] * mwj.y - ((row == j4 + 1) ? cc : 0.f)) * invh;
    m.z = (yr[u].z * invT - mwi[u] * mwj.z - ((row == j4 + 2) ? cc : 0.f)) * invh;
    m.w = (yr[u].w * invT - mwi[u] * mwj.w - ((row == j4 + 3) ? cc : 0.f)) * invh;
    *(float4*)&sm.c.M[row][j4] = m;
    float4 e;
    e.x = (row == j4 + 0) ? 1.f : 0.f;
    e.y = (row == j4 + 1) ? 1.f : 0.f;
    e.z = (row == j4 + 2) ? 1.f : 0.f;
    e.w = (row == j4 + 3) ? 1.f : 0.f;
    tp[u]  = e;   // T0 tile
    tcu[u] = m;   // T1 tile
    zz[u].x = a0c * e.x + a1c * m.x;
    zz[u].y = a0c * e.y + a1c * m.y;
    zz[u].z = a0c * e.z + a1c * m.z;
    zz[u].w = a0c * e.w + a1c * m.w;
  }

  // ---- recurrence: T_k = 2 M T_{k-1} - T_{k-2};  Z += a_k T_k ----
  float rhok = rho;
  for (int k = 2; k <= NDEG; ++k) {
    __syncthreads();
    const float(*src)[68] = (k == 2) ? sm.c.M : ((k & 1) ? sm.c.bufA : sm.c.bufB);
    float(*dst)[68] = (k & 1) ? sm.c.bufB : sm.c.bufA;
    float4 p[4];
#pragma unroll
    for (int u = 0; u < 4; ++u) p[u] = make_float4(0.f, 0.f, 0.f, 0.f);
    // P = M * T_{k-1}; use M symmetric: M[i][m] = M[m][i] -> all row-major float4 reads
#pragma unroll 4
    for (int m = 0; m < 64; ++m) {
      const float4 am = *(const float4*)&sm.c.M[m][i4];
      const float4 bm = *(const float4*)&src[m][j4];
      fma4(p[0], bm, am.x);
      fma4(p[1], bm, am.y);
      fma4(p[2], bm, am.z);
      fma4(p[3], bm, am.w);
    }
    rhok *= rho;
    const float ak = (-2.0f / (float)k) * rhok;
#pragma unroll
    for (int u = 0; u < 4; ++u) {
      float4 nn;
      nn.x = 2.f * p[u].x - tp[u].x;
      nn.y = 2.f * p[u].y - tp[u].y;
      nn.z = 2.f * p[u].z - tp[u].z;
      nn.w = 2.f * p[u].w - tp[u].w;
      zz[u].x = fmaf(ak, nn.x, zz[u].x);
      zz[u].y = fmaf(ak, nn.y, zz[u].y);
      zz[u].z = fmaf(ak, nn.z, zz[u].z);
      zz[u].w = fmaf(ak, nn.w, zz[u].w);
      tp[u]  = tcu[u];
      tcu[u] = nn;
      if (k < NDEG) *(float4*)&dst[i4 + u][j4] = nn;
    }
  }

  // ---- output: out[b][o] = sum_ij Z[i][j] * lin_w[o][i*64+j] + lin_b[o] ----
  float po[4] = {0.f, 0.f, 0.f, 0.f};
#pragma unroll
  for (int u = 0; u < 4; ++u) {
    const int base = (i4 + u) * 64 + j4;
#pragma unroll
    for (int o = 0; o < 4; ++o) {
      const float4 wv = *(const float4*)&lin_w[o * 4096 + base];
      po[o] += zz[u].x * wv.x + zz[u].y * wv.y + zz[u].z * wv.z + zz[u].w * wv.w;
    }
  }
  __syncthreads();
#pragma unroll
  for (int o = 0; o < 4; ++o) sm.c.red[t][o] = po[o];
  __syncthreads();
  if (t < 4) {
    float s = lin_b[t];
    for (int j = 0; j < 256; ++j) s += sm.c.red[j][t];
    out[b * 4 + t] = s;
  }
}

extern "C" void kernel_launch(void* const* d_in, const int* in_sizes, int n_in,
                              void* d_out, int out_size, void* d_ws, size_t ws_size,
                              hipStream_t stream) {
  const float* X     = (const float*)d_in[0];
  const float* W     = (const float*)d_in[1];
  const float* lin_w = (const float*)d_in[2];
  const float* lin_b = (const float*)d_in[3];
  float* out = (float*)d_out;
  spdnet_fused_kernel<<<512, 256, 0, stream>>>(X, W, lin_w, lin_b, out);
}

// Round 2
// 157.258 us; speedup vs baseline: 3.4050x; 3.4050x over previous
//
#include <hip/hip_runtime.h>
#include <math.h>

#define NDEG 22

typedef unsigned short u16;
typedef unsigned int u32;
typedef __attribute__((ext_vector_type(8))) short bf16x8;
typedef __attribute__((ext_vector_type(4))) float f32x4;

#define MFMA(a, b, c) __builtin_amdgcn_mfma_f32_16x16x32_bf16(a, b, c, 0, 0, 0)

struct PhA {
  u16 WtH[64][136];   // W^T hi plane, [d][c], pitch 136 bf16
  u16 WtL[64][136];   // W^T lo plane
  u16 XtH[32][136];   // X tile transposed, [t][c] hi
  u16 XtL[32][136];   // lo
  u16 XwH[64][40];    // Xw tile, [d][t] hi, pitch 40
  u16 XwL[64][40];    // lo
  float xsumP[128][4];
  float xsum[128];
  float mw[64];
};                     // 65280 B
struct PhC {
  u16 MH[64][72];     // M hi plane, pitch 72
  u16 ML[64][72];
  u16 TbH[2][64][72]; // T_k double buffer hi
  u16 TbL[2][64][72];
  float red[256][4];
};                     // 59392 B
union SmemU { PhA a; PhC c; };

static_assert(sizeof(PhA) == 65280, "PhA");
static_assert(sizeof(SmemU) <= 65536, "smem");

__device__ __forceinline__ u32 fbits(float x) { return __float_as_uint(x); }
__device__ __forceinline__ float fval(u32 u) { return __uint_as_float(u); }

// split fp32 into bf16 hi (truncated) + bf16 lo (RNE of remainder)
__device__ __forceinline__ void split2(float x, u32& h, u32& l) {
  u32 u = fbits(x);
  h = u >> 16;
  float lo = x - fval(u & 0xFFFF0000u);
  u32 v = fbits(lo);
  l = (v + 0x7FFFu + ((v >> 16) & 1u)) >> 16;
}

__device__ __forceinline__ f32x4 zero4() {
  f32x4 z; z[0] = 0.f; z[1] = 0.f; z[2] = 0.f; z[3] = 0.f; return z;
}

// write one bf16-split value; lane pair (lane, lane^1) owns adjacent cols,
// even lane emits the hi-plane word, odd lane the lo-plane word.
__device__ __forceinline__ void writePair(u32* Hw, u32* Lw, int widx, float v, int lane) {
  float pv = __shfl_xor(v, 1);
  u32 hv, lv, hp, lp;
  split2(v, hv, lv);
  split2(pv, hp, lp);
  const bool even = (lane & 1) == 0;
  u32 word = even ? (hv | (hp << 16)) : (lp | (lv << 16));
  u32* base = even ? Hw : Lw;
  base[widx] = word;
}

__global__ __launch_bounds__(256, 2) void spdnet_mfma_kernel(
    const float* __restrict__ X,
    const float* __restrict__ W,
    const float* __restrict__ lin_w,
    const float* __restrict__ lin_b,
    float* __restrict__ out)
{
  __shared__ SmemU sm;
  const int tid = threadIdx.x;
  const int lane = tid & 63;
  const int wv = tid >> 6;       // wave 0..3
  const int l15 = lane & 15;
  const int l16 = lane >> 4;     // 0..3
  const int wi = wv >> 1;        // Gram/Cheb quadrant row
  const int wj = wv & 1;         // Gram/Cheb quadrant col
  const int b = blockIdx.x;
  const float* __restrict__ Xb = X + (size_t)b * 128000u;

  // ---------------- stage W^T planes (bf16 hi/lo), one-time ----------------
  {
    u32* WtHw = (u32*)&sm.a.WtH[0][0];
    u32* WtLw = (u32*)&sm.a.WtL[0][0];
#pragma unroll
    for (int u = 0; u < 8; ++u) {
      int q = tid + 256 * u;           // 0..2047
      int c = q >> 4;                  // 0..127
      int d0 = (q & 15) * 4;
      float4 f = *(const float4*)&W[c * 64 + d0];
      float own[4] = {f.x, f.y, f.z, f.w};
      float par[4];
      par[0] = __shfl_xor(f.x, 16);    // partner has c^1, same d0
      par[1] = __shfl_xor(f.y, 16);
      par[2] = __shfl_xor(f.z, 16);
      par[3] = __shfl_xor(f.w, 16);
      const bool even = (c & 1) == 0;
#pragma unroll
      for (int i = 0; i < 4; ++i) {
        u32 ho, lo_, hp, lp;
        split2(own[i], ho, lo_);
        split2(par[i], hp, lp);
        u32 word = even ? (ho | (hp << 16)) : (lp | (lo_ << 16));
        u32* base = even ? WtHw : WtLw;
        base[(d0 + i) * 68 + (c >> 1)] = word;
      }
    }
  }
  __syncthreads();

  // preload loop-invariant W A-frags: wave wv owns d-rows [16wv, 16wv+16)
  bf16x8 wAh[4], wAl[4];
#pragma unroll
  for (int ch = 0; ch < 4; ++ch) {
    wAh[ch] = *(const bf16x8*)&sm.a.WtH[16 * wv + l15][8 * l16 + 32 * ch];
    wAl[ch] = *(const bf16x8*)&sm.a.WtL[16 * wv + l15][8 * l16 + 32 * ch];
  }

  // staging map: thread owns rows (c0, c0+1), t-octet t0..t0+7 of each 32-t tile
  const int cpair = tid >> 2;      // 0..63
  const int c0 = cpair * 2;
  const int tq = tid & 3;
  const int t0 = tq * 8;
  const float* rp0 = Xb + c0 * 1000;
  const float* rp1 = rp0 + 1000;

  float4 pr[4];
  pr[0] = *(const float4*)&rp0[t0];
  pr[1] = *(const float4*)&rp0[t0 + 4];
  pr[2] = *(const float4*)&rp1[t0];
  pr[3] = *(const float4*)&rp1[t0 + 4];

  float rs0 = 0.f, rs1 = 0.f;
  f32x4 gHH[2][2], gHL[2][2];
#pragma unroll
  for (int ti = 0; ti < 2; ++ti)
#pragma unroll
    for (int tj = 0; tj < 2; ++tj) { gHH[ti][tj] = zero4(); gHL[ti][tj] = zero4(); }

  u32* XtHw = (u32*)&sm.a.XtH[0][0];
  u32* XtLw = (u32*)&sm.a.XtL[0][0];
  u32* XwHw = (u32*)&sm.a.XwH[0][0];
  u32* XwLw = (u32*)&sm.a.XwL[0][0];

  // ---------------- main loop over 32 time-tiles of 32 ----------------
  for (int it = 0; it < 32; ++it) {
    // write X tile transposed into LDS (word-packed: this thread holds c0,c0+1)
    {
      float e0[8] = {pr[0].x, pr[0].y, pr[0].z, pr[0].w, pr[1].x, pr[1].y, pr[1].z, pr[1].w};
      float e1[8] = {pr[2].x, pr[2].y, pr[2].z, pr[2].w, pr[3].x, pr[3].y, pr[3].z, pr[3].w};
#pragma unroll
      for (int j = 0; j < 8; ++j) {
        u32 h0, l0, h1, l1;
        split2(e0[j], h0, l0);
        split2(e1[j], h1, l1);
        rs0 += e0[j];
        rs1 += e1[j];
        int widx = (t0 + j) * 68 + cpair;
        XtHw[widx] = h0 | (h1 << 16);
        XtLw[widx] = l0 | (l1 << 16);
      }
    }
    // prefetch next tile (zero-pad t >= 1000)
    if (it + 1 < 32) {
      int tg = (it + 1) * 32 + t0;
      if (tg < 1000) {
        pr[0] = *(const float4*)&rp0[tg];
        pr[1] = *(const float4*)&rp0[tg + 4];
        pr[2] = *(const float4*)&rp1[tg];
        pr[3] = *(const float4*)&rp1[tg + 4];
      } else {
        pr[0] = pr[1] = pr[2] = pr[3] = make_float4(0.f, 0.f, 0.f, 0.f);
      }
    }
    __syncthreads();   // Xt ready

    // Xw = W^T X : 3-term split MFMA; wave wv -> d-band 16wv, t-tiles {0,1}
    f32x4 xw[2] = {zero4(), zero4()};
#pragma unroll
    for (int ch = 0; ch < 4; ++ch) {
      const int ko = 8 * l16 + 32 * ch;
      bf16x8 b0h = *(const bf16x8*)&sm.a.XtH[l15][ko];
      bf16x8 b0l = *(const bf16x8*)&sm.a.XtL[l15][ko];
      bf16x8 b1h = *(const bf16x8*)&sm.a.XtH[16 + l15][ko];
      bf16x8 b1l = *(const bf16x8*)&sm.a.XtL[16 + l15][ko];
      xw[0] = MFMA(wAh[ch], b0h, xw[0]);
      xw[0] = MFMA(wAh[ch], b0l, xw[0]);
      xw[0] = MFMA(wAl[ch], b0h, xw[0]);
      xw[1] = MFMA(wAh[ch], b1h, xw[1]);
      xw[1] = MFMA(wAh[ch], b1l, xw[1]);
      xw[1] = MFMA(wAl[ch], b1h, xw[1]);
    }
    // split Xw frags -> bf16 planes [d][t]
#pragma unroll
    for (int tj = 0; tj < 2; ++tj)
#pragma unroll
      for (int r = 0; r < 4; ++r) {
        int row = 16 * wv + 4 * l16 + r;
        int col = 16 * tj + l15;
        writePair(XwHw, XwLw, row * 20 + (col >> 1), xw[tj][r], lane);
      }
    __syncthreads();   // Xw ready

    // Gram accumulate: wave quadrant (wi,wj), 2-term split (hh + hl)
    {
      const int ko = 8 * l16;
      bf16x8 aG[2], bGh[2], bGl[2];
#pragma unroll
      for (int ti = 0; ti < 2; ++ti)
        aG[ti] = *(const bf16x8*)&sm.a.XwH[32 * wi + 16 * ti + l15][ko];
#pragma unroll
      for (int tj = 0; tj < 2; ++tj) {
        bGh[tj] = *(const bf16x8*)&sm.a.XwH[32 * wj + 16 * tj + l15][ko];
        bGl[tj] = *(const bf16x8*)&sm.a.XwL[32 * wj + 16 * tj + l15][ko];
      }
#pragma unroll
      for (int ti = 0; ti < 2; ++ti)
#pragma unroll
        for (int tj = 0; tj < 2; ++tj) {
          gHH[ti][tj] = MFMA(aG[ti], bGh[tj], gHH[ti][tj]);
          gHL[ti][tj] = MFMA(aG[ti], bGl[tj], gHL[ti][tj]);
        }
    }
  }

  // ---------------- means + symmetric combine ----------------
  float* Ghl = (float*)&sm.a.XtH[0][0];   // [64][68] fp32, overlays Xt planes
#pragma unroll
  for (int ti = 0; ti < 2; ++ti)
#pragma unroll
    for (int tj = 0; tj < 2; ++tj)
#pragma unroll
      for (int r = 0; r < 4; ++r) {
        int i = 32 * wi + 16 * ti + 4 * l16 + r;
        int j = 32 * wj + 16 * tj + l15;
        Ghl[i * 68 + j] = gHL[ti][tj][r];
      }
  sm.a.xsumP[c0][tq] = rs0;
  sm.a.xsumP[c0 + 1][tq] = rs1;
  __syncthreads();

  if (tid < 128) {
    sm.a.xsum[tid] = sm.a.xsumP[tid][0] + sm.a.xsumP[tid][1] +
                     sm.a.xsumP[tid][2] + sm.a.xsumP[tid][3];
  }
  __syncthreads();
  if (tid < 64) {
    float s = 0.f;
    for (int c = 0; c < 128; ++c) {
      float w = fval((u32)sm.a.WtH[tid][c] << 16) + fval((u32)sm.a.WtL[tid][c] << 16);
      s = fmaf(w, sm.a.xsum[c], s);
    }
    sm.a.mw[tid] = s * 1.0e-3f;
  }
  __syncthreads();

  // ---------------- M = (Y - cc I)/hw, Chebyshev init ----------------
  const float CC = 1.125f;
  const float IH = 1.0f / 0.875f;
  const float uu = 0.875f / 1.125f;
  const float rho = (sqrtf(1.0f - uu * uu) - 1.0f) / uu;   // ~ -0.47759
  const float a0c = logf(CC / (1.0f + rho * rho));
  const float a1c = -2.0f * rho;

  float mwi[2][4], mwj[2];
#pragma unroll
  for (int ti = 0; ti < 2; ++ti)
#pragma unroll
    for (int r = 0; r < 4; ++r)
      mwi[ti][r] = sm.a.mw[32 * wi + 16 * ti + 4 * l16 + r];
#pragma unroll
  for (int tj = 0; tj < 2; ++tj)
    mwj[tj] = sm.a.mw[32 * wj + 16 * tj + l15];

  f32x4 zz[2][2], tp[2][2], tcu[2][2];
#pragma unroll
  for (int ti = 0; ti < 2; ++ti)
#pragma unroll
    for (int tj = 0; tj < 2; ++tj)
#pragma unroll
      for (int r = 0; r < 4; ++r) {
        int i = 32 * wi + 16 * ti + 4 * l16 + r;
        int j = 32 * wj + 16 * tj + l15;
        float gsym = gHH[ti][tj][r] + gHL[ti][tj][r] + Ghl[j * 68 + i];
        float y = gsym * 1.0e-3f - mwi[ti][r] * mwj[tj];
        float m = (y - ((i == j) ? CC : 0.f)) * IH;
        float e = (i == j) ? 1.f : 0.f;
        tp[ti][tj][r] = e;
        tcu[ti][tj][r] = m;
        zz[ti][tj][r] = a0c * e + a1c * m;
      }

  // write M planes (overlays W region; W is dead now)
  {
    u32* MHw = (u32*)&sm.c.MH[0][0];
    u32* MLw = (u32*)&sm.c.ML[0][0];
#pragma unroll
    for (int ti = 0; ti < 2; ++ti)
#pragma unroll
      for (int tj = 0; tj < 2; ++tj)
#pragma unroll
        for (int r = 0; r < 4; ++r) {
          int row = 32 * wi + 16 * ti + 4 * l16 + r;
          int col = 32 * wj + 16 * tj + l15;
          writePair(MHw, MLw, row * 36 + (col >> 1), tcu[ti][tj][r], lane);
        }
  }
  __syncthreads();   // M planes ready (also: Ghl fully consumed)

  // preload loop-invariant M A-frags
  bf16x8 aMh[2][2], aMl[2][2];
#pragma unroll
  for (int ti = 0; ti < 2; ++ti)
#pragma unroll
    for (int ch = 0; ch < 2; ++ch) {
      aMh[ti][ch] = *(const bf16x8*)&sm.c.MH[32 * wi + 16 * ti + l15][8 * l16 + 32 * ch];
      aMl[ti][ch] = *(const bf16x8*)&sm.c.ML[32 * wi + 16 * ti + l15][8 * l16 + 32 * ch];
    }

  // ---------------- Chebyshev recurrence: T_k = 2 M T_{k-1} - T_{k-2} ----------------
  float rhok = rho;
  for (int k = 2; k <= NDEG; ++k) {
    const u16 (*srcH)[72] = (k == 2) ? sm.c.MH : sm.c.TbH[(k - 1) & 1];
    const u16 (*srcL)[72] = (k == 2) ? sm.c.ML : sm.c.TbL[(k - 1) & 1];
    f32x4 p[2][2];
#pragma unroll
    for (int ti = 0; ti < 2; ++ti)
#pragma unroll
      for (int tj = 0; tj < 2; ++tj) p[ti][tj] = zero4();
#pragma unroll
    for (int ch = 0; ch < 2; ++ch) {
      bf16x8 bh[2], bl[2];
#pragma unroll
      for (int tj = 0; tj < 2; ++tj) {
        bh[tj] = *(const bf16x8*)&srcH[32 * wj + 16 * tj + l15][8 * l16 + 32 * ch];
        bl[tj] = *(const bf16x8*)&srcL[32 * wj + 16 * tj + l15][8 * l16 + 32 * ch];
      }
#pragma unroll
      for (int ti = 0; ti < 2; ++ti)
#pragma unroll
        for (int tj = 0; tj < 2; ++tj) {
          p[ti][tj] = MFMA(aMh[ti][ch], bh[tj], p[ti][tj]);
          p[ti][tj] = MFMA(aMh[ti][ch], bl[tj], p[ti][tj]);
          p[ti][tj] = MFMA(aMl[ti][ch], bh[tj], p[ti][tj]);
        }
    }
    rhok *= rho;
    const float ak = (-2.0f / (float)k) * rhok;
    u32* dH = (u32*)&sm.c.TbH[k & 1][0][0];
    u32* dL = (u32*)&sm.c.TbL[k & 1][0][0];
#pragma unroll
    for (int ti = 0; ti < 2; ++ti)
#pragma unroll
      for (int tj = 0; tj < 2; ++tj) {
        f32x4 tn;
#pragma unroll
        for (int r = 0; r < 4; ++r) {
          tn[r] = 2.f * p[ti][tj][r] - tp[ti][tj][r];
          zz[ti][tj][r] = fmaf(ak, tn[r], zz[ti][tj][r]);
        }
        tp[ti][tj] = tcu[ti][tj];
        tcu[ti][tj] = tn;
        if (k < NDEG) {
#pragma unroll
          for (int r = 0; r < 4; ++r) {
            int row = 32 * wi + 16 * ti + 4 * l16 + r;
            int col = 32 * wj + 16 * tj + l15;
            writePair(dH, dL, row * 36 + (col >> 1), tn[r], lane);
          }
        }
      }
    if (k < NDEG) __syncthreads();
  }

  // ---------------- output: out[b][o] = sum_ij Z_ij lin_w[o][i*64+j] + b_o ----------------
  float po[4] = {0.f, 0.f, 0.f, 0.f};
#pragma unroll
  for (int ti = 0; ti < 2; ++ti)
#pragma unroll
    for (int tj = 0; tj < 2; ++tj)
#pragma unroll
      for (int r = 0; r < 4; ++r) {
        int i = 32 * wi + 16 * ti + 4 * l16 + r;
        int j = 32 * wj + 16 * tj + l15;
        const float zv = zz[ti][tj][r];
        const int base = i * 64 + j;
#pragma unroll
        for (int o = 0; o < 4; ++o)
          po[o] = fmaf(zv, lin_w[o * 4096 + base], po[o]);
      }
#pragma unroll
  for (int o = 0; o < 4; ++o) sm.c.red[tid][o] = po[o];
  __syncthreads();
  if (tid < 4) {
    float s = lin_b[tid];
    for (int q = 0; q < 256; ++q) s += sm.c.red[q][tid];
    out[b * 4 + tid] = s;
  }
}

extern "C" void kernel_launch(void* const* d_in, const int* in_sizes, int n_in,
                              void* d_out, int out_size, void* d_ws, size_t ws_size,
                              hipStream_t stream) {
  const float* X     = (const float*)d_in[0];
  const float* W     = (const float*)d_in[1];
  const float* lin_w = (const float*)d_in[2];
  const float* lin_b = (const float*)d_in[3];
  float* out = (float*)d_out;
  spdnet_mfma_kernel<<<512, 256, 0, stream>>>(X, W, lin_w, lin_b, out);
}

// Round 3
// 101.923 us; speedup vs baseline: 5.2536x; 1.5429x over previous
//
#include <hip/hip_runtime.h>
#include <math.h>

#define NDEG 22

typedef unsigned short u16;
typedef unsigned int u32;
typedef _Float16 f16;
typedef __attribute__((ext_vector_type(8))) _Float16 f16x8;
typedef __attribute__((ext_vector_type(8))) short bf16x8;
typedef __attribute__((ext_vector_type(4))) float f32x4;

#define MFMA_F16(a, b, c)  __builtin_amdgcn_mfma_f32_16x16x32_f16(a, b, c, 0, 0, 0)
#define MFMA_BF16(a, b, c) __builtin_amdgcn_mfma_f32_16x16x32_bf16(a, b, c, 0, 0, 0)

#define GLL16(g, l) __builtin_amdgcn_global_load_lds(                    \
    (const __attribute__((address_space(1))) void*)(g),                  \
    (__attribute__((address_space(3))) void*)(l), 16, 0, 0)

__device__ __forceinline__ u32 fbits(float x) { return __float_as_uint(x); }
__device__ __forceinline__ float fval(u32 u) { return __uint_as_float(u); }
__device__ __forceinline__ f32x4 zero4() {
  f32x4 z; z[0] = 0.f; z[1] = 0.f; z[2] = 0.f; z[3] = 0.f; return z;
}
__device__ __forceinline__ u16 f16bits(f16 x) { u16 u; __builtin_memcpy(&u, &x, 2); return u; }
__device__ __forceinline__ float f16tof(u16 u) { f16 h; __builtin_memcpy(&h, &u, 2); return (float)h; }

// bf16 hi (trunc) + bf16 lo (RNE remainder) split  [round-2 known-good]
__device__ __forceinline__ void split2(float x, u32& h, u32& l) {
  u32 u = fbits(x);
  h = u >> 16;
  float lo = x - fval(u & 0xFFFF0000u);
  u32 v = fbits(lo);
  l = (v + 0x7FFFu + ((v >> 16) & 1u)) >> 16;
}
// lane pair (l, l^1) owns adjacent cols; even lane emits hi-plane word, odd the lo word
__device__ __forceinline__ void writePair(u32* Hw, u32* Lw, int widx, float v, int lane) {
  float pv = __shfl_xor(v, 1);
  u32 hv, lv, hp, lp;
  split2(v, hv, lv);
  split2(pv, hp, lp);
  const bool even = (lane & 1) == 0;
  u32 word = even ? (hv | (hp << 16)) : (lp | (lv << 16));
  u32* base = even ? Hw : Lw;
  base[widx] = word;
}

// ================= kernel A: per-sample raw Cov G = X X^T and row sums =================
__global__ __launch_bounds__(256, 2) void spdnet_cov_kernel(
    const float* __restrict__ X, float* __restrict__ G, float* __restrict__ XS)
{
  __shared__ float buf[3][4096];   // 3 x 16KB tiles, XOR-swizzled [128 rows][32 t] fp32
  __shared__ float xsP[128][2];
  const int tid = threadIdx.x;
  const int lane = tid & 63;
  const int wv = tid >> 6;
  const int l15 = lane & 15;
  const int b = blockIdx.x;
  const float* __restrict__ Xb = X + (size_t)b * 128000u;

  // per-lane DMA source mapping: physical LDS p -> logical l = p ^ (((p>>7)&7)<<4)
  int grow[4], gcol[4];
#pragma unroll
  for (int i = 0; i < 4; ++i) {
    int p = (wv * 4 + i) * 1024 + lane * 16;
    int l = p ^ (((p >> 7) & 7) << 4);
    grow[i] = l >> 7;
    gcol[i] = (l & 127) >> 2;
  }

  f32x4 acc[2][8];
#pragma unroll
  for (int ti = 0; ti < 2; ++ti)
#pragma unroll
    for (int tb = 0; tb < 8; ++tb) acc[ti][tb] = zero4();
  float xacc = 0.f;

  auto ISSUE = [&](int tile, int bi) {
#pragma unroll
    for (int i = 0; i < 4; ++i) {
      const float* g = Xb + grow[i] * 1000 + tile * 32 + gcol[i];
      GLL16(g, &buf[bi][(wv * 4 + i) * 256]);
    }
  };
  auto FRAG32 = [&](const float* bb, int row) -> f16x8 {
    const int m = (row & 7) << 4;
    const int b0 = row * 128 + 32 * (lane >> 4);
    float4 x0 = *(const float4*)((const char*)bb + (b0 ^ m));
    float4 x1 = *(const float4*)((const char*)bb + ((b0 + 16) ^ m));
    f16x8 r;
    r[0] = (f16)x0.x; r[1] = (f16)x0.y; r[2] = (f16)x0.z; r[3] = (f16)x0.w;
    r[4] = (f16)x1.x; r[5] = (f16)x1.y; r[6] = (f16)x1.z; r[7] = (f16)x1.w;
    return r;
  };
  auto COMPUTE = [&](const float* bb) {
    f16x8 a0 = FRAG32(bb, 32 * wv + l15);
    f16x8 a1 = FRAG32(bb, 32 * wv + 16 + l15);
#pragma unroll
    for (int tb = 0; tb < 8; ++tb) {
      f16x8 bf = FRAG32(bb, 16 * tb + l15);
      acc[0][tb] = MFMA_F16(a0, bf, acc[0][tb]);
      acc[1][tb] = MFMA_F16(a1, bf, acc[1][tb]);
    }
    const int row = tid >> 1, h = tid & 1, m = (row & 7) << 4;
#pragma unroll
    for (int q = 0; q < 4; ++q) {
      float4 v = *(const float4*)((const char*)bb + ((row * 128 + h * 64 + q * 16) ^ m));
      xacc += v.x + v.y + v.z + v.w;
    }
  };

  // prologue: tiles 0,1 in flight
  ISSUE(0, 0);
  ISSUE(1, 1);

  for (int it = 0; it < 31; ++it) {
    if (it < 30) asm volatile("s_waitcnt vmcnt(4)" ::: "memory");
    else         asm volatile("s_waitcnt vmcnt(0)" ::: "memory");
    asm volatile("s_waitcnt lgkmcnt(0)" ::: "memory");
    __builtin_amdgcn_s_barrier();
    COMPUTE(buf[it % 3]);
    if (it + 2 <= 30) ISSUE(it + 2, (it + 2) % 3);
  }

  // tail: t = 992..999 valid, pad 24 zeros; staged via registers into buf[1]
  __syncthreads();
  {
    float* bt = buf[1];
    const int row = tid >> 1, h = tid & 1, m = (row & 7) << 4;
    float4 v = *(const float4*)&Xb[row * 1000 + 992 + 4 * h];
    *(float4*)((char*)bt + ((row * 128 + h * 16) ^ m)) = v;
    float4 z = make_float4(0.f, 0.f, 0.f, 0.f);
#pragma unroll
    for (int q = 0; q < 3; ++q) {
      int cb = 32 + h * 48 + q * 16;
      *(float4*)((char*)bt + ((row * 128 + cb) ^ m)) = z;
    }
  }
  __syncthreads();
  COMPUTE(buf[1]);

  // writeout G (full square) + row-sum partials
  {
    float* Gb = G + (size_t)b * 16384u;
    const int l16 = lane >> 4;
#pragma unroll
    for (int ti = 0; ti < 2; ++ti)
#pragma unroll
      for (int tb = 0; tb < 8; ++tb)
#pragma unroll
        for (int r = 0; r < 4; ++r) {
          int c  = 32 * wv + 16 * ti + 4 * l16 + r;
          int cp = 16 * tb + l15;
          Gb[c * 128 + cp] = acc[ti][tb][r];
        }
  }
  xsP[tid >> 1][tid & 1] = xacc;
  __syncthreads();
  if (tid < 128) XS[b * 128 + tid] = xsP[tid][0] + xsP[tid][1];
}

// ================= kernel C: projection + matrix-log (Chebyshev) + classifier =================
struct KCa {
  u16 Cov[128][136];   // fp16, G*1e-3; later overlaid by Pt[64][136]
  u16 Wt[64][136];     // fp16, W^T [d][c]
};
struct KCc {
  u16 MH[64][72];
  u16 ML[64][72];
  u16 TbH[2][64][72];
  u16 TbL[2][64][72];
};
union KCU { KCa a; KCc c; };

__global__ __launch_bounds__(256, 2) void spdnet_log_kernel(
    const float* __restrict__ G, const float* __restrict__ XS,
    const float* __restrict__ W, const float* __restrict__ lin_w,
    const float* __restrict__ lin_b, float* __restrict__ out)
{
  __shared__ KCU smu;
  __shared__ float redL[256][4];
  __shared__ float mwL[64];
  __shared__ float xsL[128];
  const int tid = threadIdx.x;
  const int lane = tid & 63;
  const int wv = tid >> 6;
  const int l15 = lane & 15;
  const int l16 = lane >> 4;
  const int b = blockIdx.x;
  const float* __restrict__ Gb = G + (size_t)b * 16384u;

  // ---- stage Cov (fp16, scaled 1e-3), Wt (fp16 transpose), xsum ----
  {
    u32* CovW = (u32*)&smu.a.Cov[0][0];
    const int r = tid >> 1, h = tid & 1;
    const float4* gp = (const float4*)(Gb + r * 128 + 64 * h);
#pragma unroll
    for (int q = 0; q < 16; ++q) {
      float4 v = gp[q];
      u32 w0 = (u32)f16bits((f16)(v.x * 1e-3f)) | ((u32)f16bits((f16)(v.y * 1e-3f)) << 16);
      u32 w1 = (u32)f16bits((f16)(v.z * 1e-3f)) | ((u32)f16bits((f16)(v.w * 1e-3f)) << 16);
      CovW[r * 68 + 32 * h + 2 * q]     = w0;
      CovW[r * 68 + 32 * h + 2 * q + 1] = w1;
    }
    u16* WtP = &smu.a.Wt[0][0];
    const int c = tid & 127, dh = tid >> 7;
    const float4* wp = (const float4*)(W + c * 64 + 32 * dh);
#pragma unroll
    for (int q = 0; q < 8; ++q) {
      float4 v = wp[q];
      int d0 = 32 * dh + 4 * q;
      WtP[(d0    ) * 136 + c] = f16bits((f16)v.x);
      WtP[(d0 + 1) * 136 + c] = f16bits((f16)v.y);
      WtP[(d0 + 2) * 136 + c] = f16bits((f16)v.z);
      WtP[(d0 + 3) * 136 + c] = f16bits((f16)v.w);
    }
    if (tid < 128) xsL[tid] = XS[b * 128 + tid];
  }
  __syncthreads();

  // mw = W^T xsum * 1e-3 (wave 0) while others start P
  if (tid < 64) {
    float s = 0.f;
    for (int c = 0; c < 128; ++c)
      s = fmaf(f16tof(smu.a.Wt[tid][c]), xsL[c], s);
    mwL[tid] = s * 1.0e-3f;
  }

  // ---- P = Cov * W  (fp16 MFMA; wave wv owns rows 32wv..32wv+32) ----
  const u16* CovP = &smu.a.Cov[0][0];
  const u16* WtP  = &smu.a.Wt[0][0];
  f32x4 pAcc[2][4];
#pragma unroll
  for (int ti = 0; ti < 2; ++ti)
#pragma unroll
    for (int n = 0; n < 4; ++n) pAcc[ti][n] = zero4();
#pragma unroll
  for (int ch = 0; ch < 4; ++ch) {
    f16x8 aC[2], bw[4];
#pragma unroll
    for (int ti = 0; ti < 2; ++ti)
      aC[ti] = *(const f16x8*)&CovP[(32 * wv + 16 * ti + l15) * 136 + 8 * l16 + 32 * ch];
#pragma unroll
    for (int n = 0; n < 4; ++n)
      bw[n] = *(const f16x8*)&WtP[(16 * n + l15) * 136 + 8 * l16 + 32 * ch];
#pragma unroll
    for (int ti = 0; ti < 2; ++ti)
#pragma unroll
      for (int n = 0; n < 4; ++n)
        pAcc[ti][n] = MFMA_F16(aC[ti], bw[n], pAcc[ti][n]);
  }
  __syncthreads();   // all Cov reads done -> Pt may overlay

  // ---- Pt[d][c] = P[c][d]  (fp16, overlays Cov) ----
  {
    u16* PtP = (u16*)&smu.a.Cov[0][0];
#pragma unroll
    for (int ti = 0; ti < 2; ++ti)
#pragma unroll
      for (int n = 0; n < 4; ++n)
#pragma unroll
        for (int r = 0; r < 4; ++r) {
          int c = 32 * wv + 16 * ti + 4 * l16 + r;
          int d = 16 * n + l15;
          PtP[d * 136 + c] = f16bits((f16)pAcc[ti][n][r]);
        }
  }
  __syncthreads();

  // ---- Y = W^T P  (wave wv owns rows 16wv..16wv+16) ----
  const u16* PtP = (const u16*)&smu.a.Cov[0][0];
  f32x4 yAcc[4];
#pragma unroll
  for (int n = 0; n < 4; ++n) yAcc[n] = zero4();
#pragma unroll
  for (int ch = 0; ch < 4; ++ch) {
    f16x8 aW = *(const f16x8*)&WtP[(16 * wv + l15) * 136 + 8 * l16 + 32 * ch];
#pragma unroll
    for (int n = 0; n < 4; ++n) {
      f16x8 bP = *(const f16x8*)&PtP[(16 * n + l15) * 136 + 8 * l16 + 32 * ch];
      yAcc[n] = MFMA_F16(aW, bP, yAcc[n]);
    }
  }
  __syncthreads();   // Wt/Pt dead -> Chebyshev planes may overlay

  // ---- M init + Chebyshev matrix-log (bf16 3-term, round-2 numerics) ----
  const float CC = 1.125f;
  const float IH = 1.0f / 0.875f;
  const float uu = 0.875f / 1.125f;
  const float rho = (sqrtf(1.0f - uu * uu) - 1.0f) / uu;   // ~ -0.47759
  const float a0c = logf(CC / (1.0f + rho * rho));
  const float a1c = -2.0f * rho;

  f32x4 zz[4], tp[4], tcu[4];
  {
    u32* MHw = (u32*)&smu.c.MH[0][0];
    u32* MLw = (u32*)&smu.c.ML[0][0];
#pragma unroll
    for (int n = 0; n < 4; ++n)
#pragma unroll
      for (int r = 0; r < 4; ++r) {
        int i = 16 * wv + 4 * l16 + r, j = 16 * n + l15;
        float y = yAcc[n][r] - mwL[i] * mwL[j];
        float m = (y - ((i == j) ? CC : 0.f)) * IH;
        float e = (i == j) ? 1.f : 0.f;
        tp[n][r] = e;
        tcu[n][r] = m;
        zz[n][r] = a0c * e + a1c * m;
        writePair(MHw, MLw, i * 36 + (j >> 1), m, lane);
      }
  }
  __syncthreads();

  bf16x8 aMh[2], aMl[2];
#pragma unroll
  for (int ch = 0; ch < 2; ++ch) {
    aMh[ch] = *(const bf16x8*)&smu.c.MH[16 * wv + l15][8 * l16 + 32 * ch];
    aMl[ch] = *(const bf16x8*)&smu.c.ML[16 * wv + l15][8 * l16 + 32 * ch];
  }

  float rhok = rho;
  for (int k = 2; k <= NDEG; ++k) {
    const u16 (*srcH)[72] = (k == 2) ? smu.c.MH : smu.c.TbH[(k - 1) & 1];
    const u16 (*srcL)[72] = (k == 2) ? smu.c.ML : smu.c.TbL[(k - 1) & 1];
    f32x4 p[4];
#pragma unroll
    for (int n = 0; n < 4; ++n) p[n] = zero4();
#pragma unroll
    for (int ch = 0; ch < 2; ++ch) {
#pragma unroll
      for (int n = 0; n < 4; ++n) {
        bf16x8 bh = *(const bf16x8*)&srcH[16 * n + l15][8 * l16 + 32 * ch];
        bf16x8 bl = *(const bf16x8*)&srcL[16 * n + l15][8 * l16 + 32 * ch];
        p[n] = MFMA_BF16(aMh[ch], bh, p[n]);
        p[n] = MFMA_BF16(aMh[ch], bl, p[n]);
        p[n] = MFMA_BF16(aMl[ch], bh, p[n]);
      }
    }
    rhok *= rho;
    const float ak = (-2.0f / (float)k) * rhok;
    u32* dH = (u32*)&smu.c.TbH[k & 1][0][0];
    u32* dL = (u32*)&smu.c.TbL[k & 1][0][0];
#pragma unroll
    for (int n = 0; n < 4; ++n) {
      f32x4 tn;
#pragma unroll
      for (int r = 0; r < 4; ++r) {
        tn[r] = 2.f * p[n][r] - tp[n][r];
        zz[n][r] = fmaf(ak, tn[r], zz[n][r]);
      }
      tp[n] = tcu[n];
      tcu[n] = tn;
      if (k < NDEG) {
#pragma unroll
        for (int r = 0; r < 4; ++r) {
          int row = 16 * wv + 4 * l16 + r, col = 16 * n + l15;
          writePair(dH, dL, row * 36 + (col >> 1), tn[r], lane);
        }
      }
    }
    if (k < NDEG) __syncthreads();
  }

  // ---- classifier: out[b][o] = sum_ij Z_ij lin_w[o][i*64+j] + lin_b[o] ----
  float po[4] = {0.f, 0.f, 0.f, 0.f};
#pragma unroll
  for (int n = 0; n < 4; ++n)
#pragma unroll
    for (int r = 0; r < 4; ++r) {
      int i = 16 * wv + 4 * l16 + r, j = 16 * n + l15;
      const float zv = zz[n][r];
      const int base = i * 64 + j;
#pragma unroll
      for (int o = 0; o < 4; ++o)
        po[o] = fmaf(zv, lin_w[o * 4096 + base], po[o]);
    }
#pragma unroll
  for (int o = 0; o < 4; ++o) redL[tid][o] = po[o];
  __syncthreads();
  if (tid < 4) {
    float s = lin_b[tid];
    for (int q = 0; q < 256; ++q) s += redL[q][tid];
    out[b * 4 + tid] = s;
  }
}

extern "C" void kernel_launch(void* const* d_in, const int* in_sizes, int n_in,
                              void* d_out, int out_size, void* d_ws, size_t ws_size,
                              hipStream_t stream) {
  const float* X     = (const float*)d_in[0];
  const float* W     = (const float*)d_in[1];
  const float* lin_w = (const float*)d_in[2];
  const float* lin_b = (const float*)d_in[3];
  float* out = (float*)d_out;
  float* G  = (float*)d_ws;                       // 512*128*128 f32 = 32 MB
  float* XS = (float*)d_ws + (size_t)512 * 16384; // 512*128 f32
  spdnet_cov_kernel<<<512, 256, 0, stream>>>(X, G, XS);
  spdnet_log_kernel<<<512, 256, 0, stream>>>(G, XS, W, lin_w, lin_b, out);
}

// Round 4
// 72.020 us; speedup vs baseline: 7.4349x; 1.4152x over previous
//
#include <hip/hip_runtime.h>
#include <math.h>

#define NDEG 14

typedef unsigned short u16;
typedef unsigned int u32;
typedef _Float16 f16;
typedef __attribute__((ext_vector_type(8))) _Float16 f16x8;
typedef __attribute__((ext_vector_type(8))) short bf16x8;
typedef __attribute__((ext_vector_type(4))) float f32x4;

#define MFMA_F16(a, b, c)  __builtin_amdgcn_mfma_f32_16x16x32_f16(a, b, c, 0, 0, 0)
#define MFMA_BF16(a, b, c) __builtin_amdgcn_mfma_f32_16x16x32_bf16(a, b, c, 0, 0, 0)

#define GLL16(g, l) __builtin_amdgcn_global_load_lds(                    \
    (const __attribute__((address_space(1))) void*)(g),                  \
    (__attribute__((address_space(3))) void*)(l), 16, 0, 0)

__device__ __forceinline__ u32 fbits(float x) { return __float_as_uint(x); }
__device__ __forceinline__ float fval(u32 u) { return __uint_as_float(u); }
__device__ __forceinline__ f32x4 zero4() {
  f32x4 z; z[0] = 0.f; z[1] = 0.f; z[2] = 0.f; z[3] = 0.f; return z;
}
__device__ __forceinline__ u16 f16bits(f16 x) { u16 u; __builtin_memcpy(&u, &x, 2); return u; }
__device__ __forceinline__ float f16tof(u16 u) { f16 h; __builtin_memcpy(&h, &u, 2); return (float)h; }

// bf16 hi (trunc) + bf16 lo (RNE remainder) split  [round-2/3 known-good]
__device__ __forceinline__ void split2(float x, u32& h, u32& l) {
  u32 u = fbits(x);
  h = u >> 16;
  float lo = x - fval(u & 0xFFFF0000u);
  u32 v = fbits(lo);
  l = (v + 0x7FFFu + ((v >> 16) & 1u)) >> 16;
}
// lane pair (l, l^1) owns adjacent cols; even lane emits hi-plane word, odd the lo word
__device__ __forceinline__ void writePair(u32* Hw, u32* Lw, int widx, float v, int lane) {
  float pv = __shfl_xor(v, 1);
  u32 hv, lv, hp, lp;
  split2(v, hv, lv);
  split2(pv, hp, lp);
  const bool even = (lane & 1) == 0;
  u32 word = even ? (hv | (hp << 16)) : (lp | (lv << 16));
  u32* base = even ? Hw : Lw;
  base[widx] = word;
}

struct CovPh {
  float buf[3][4096];   // 3 x 16KB X tiles, XOR-swizzled [128 rows][32 t] fp32
  float xsP[128][2];
};                       // 50176 B
struct ProjPh {
  u16 Cov[128][136];    // fp16, Cov*1e-3; later overlaid by Pt[64][136]
  u16 Wt[64][136];      // fp16, W^T [d][c]
};                       // 52224 B
struct ChebPh {
  u16 MH[64][72];
  u16 ML[64][72];
  u16 TbH[2][64][72];
  u16 TbL[2][64][72];
};                       // 55296 B
union SmemU { CovPh a; ProjPh p; ChebPh c; };

__global__ __launch_bounds__(256, 2) void spdnet_fused2_kernel(
    const float* __restrict__ X, const float* __restrict__ W,
    const float* __restrict__ lin_w, const float* __restrict__ lin_b,
    float* __restrict__ out)
{
  __shared__ SmemU sm;
  __shared__ float mwL[64];
  __shared__ float xsL[128];
  __shared__ float redL[256][4];

  const int tid = threadIdx.x;
  const int lane = tid & 63;
  const int wv = tid >> 6;
  const int l15 = lane & 15;
  const int l16 = lane >> 4;
  const int b = blockIdx.x;
  const float* __restrict__ Xb = X + (size_t)b * 128000u;

  // ================= phase A: Cov = X X^T (fp16 MFMA) + row sums =================
  // per-lane DMA source mapping: physical LDS p -> logical l = p ^ (((p>>7)&7)<<4)
  int grow[4], gcol[4];
#pragma unroll
  for (int i = 0; i < 4; ++i) {
    int p = (wv * 4 + i) * 1024 + lane * 16;
    int l = p ^ (((p >> 7) & 7) << 4);
    grow[i] = l >> 7;
    gcol[i] = (l & 127) >> 2;
  }

  f32x4 acc[2][8];
#pragma unroll
  for (int ti = 0; ti < 2; ++ti)
#pragma unroll
    for (int tb = 0; tb < 8; ++tb) acc[ti][tb] = zero4();
  float xacc = 0.f;

  auto ISSUE = [&](int tile, int bi) {
#pragma unroll
    for (int i = 0; i < 4; ++i) {
      const float* g = Xb + grow[i] * 1000 + tile * 32 + gcol[i];
      GLL16(g, &sm.a.buf[bi][(wv * 4 + i) * 256]);
    }
  };
  auto FRAG32 = [&](const float* bb, int row) -> f16x8 {
    const int m = (row & 7) << 4;
    const int b0 = row * 128 + 32 * (lane >> 4);
    float4 x0 = *(const float4*)((const char*)bb + (b0 ^ m));
    float4 x1 = *(const float4*)((const char*)bb + ((b0 + 16) ^ m));
    f16x8 r;
    r[0] = (f16)x0.x; r[1] = (f16)x0.y; r[2] = (f16)x0.z; r[3] = (f16)x0.w;
    r[4] = (f16)x1.x; r[5] = (f16)x1.y; r[6] = (f16)x1.z; r[7] = (f16)x1.w;
    return r;
  };
  auto COMPUTE = [&](const float* bb) {
    f16x8 a0 = FRAG32(bb, 32 * wv + l15);
    f16x8 a1 = FRAG32(bb, 32 * wv + 16 + l15);
#pragma unroll
    for (int tb = 0; tb < 8; ++tb) {
      f16x8 bf = FRAG32(bb, 16 * tb + l15);
      acc[0][tb] = MFMA_F16(a0, bf, acc[0][tb]);
      acc[1][tb] = MFMA_F16(a1, bf, acc[1][tb]);
    }
    const int row = tid >> 1, h = tid & 1, m = (row & 7) << 4;
#pragma unroll
    for (int q = 0; q < 4; ++q) {
      float4 v = *(const float4*)((const char*)bb + ((row * 128 + h * 64 + q * 16) ^ m));
      xacc += v.x + v.y + v.z + v.w;
    }
  };

  ISSUE(0, 0);
  ISSUE(1, 1);
  for (int it = 0; it < 31; ++it) {
    if (it < 30) asm volatile("s_waitcnt vmcnt(4)" ::: "memory");
    else         asm volatile("s_waitcnt vmcnt(0)" ::: "memory");
    asm volatile("s_waitcnt lgkmcnt(0)" ::: "memory");
    __builtin_amdgcn_s_barrier();
    COMPUTE(sm.a.buf[it % 3]);
    if (it + 2 <= 30) ISSUE(it + 2, (it + 2) % 3);
  }
  // tail: t = 992..999 valid, pad 24 zeros
  __syncthreads();
  {
    float* bt = sm.a.buf[1];
    const int row = tid >> 1, h = tid & 1, m = (row & 7) << 4;
    float4 v = *(const float4*)&Xb[row * 1000 + 992 + 4 * h];
    *(float4*)((char*)bt + ((row * 128 + h * 16) ^ m)) = v;
    float4 z = make_float4(0.f, 0.f, 0.f, 0.f);
#pragma unroll
    for (int q = 0; q < 3; ++q) {
      int cb = 32 + h * 48 + q * 16;
      *(float4*)((char*)bt + ((row * 128 + cb) ^ m)) = z;
    }
  }
  __syncthreads();
  COMPUTE(sm.a.buf[1]);

  // row sums -> xsL (separate smem, survives union overlay)
  sm.a.xsP[tid >> 1][tid & 1] = xacc;
  __syncthreads();
  if (tid < 128) xsL[tid] = sm.a.xsP[tid][0] + sm.a.xsP[tid][1];
  __syncthreads();   // all phase-A LDS reads done -> overlay allowed

  // ================= phase P: stage Cov (fp16, *1e-3) from regs + Wt =================
  {
    u16* CovP = &sm.p.Cov[0][0];
#pragma unroll
    for (int ti = 0; ti < 2; ++ti)
#pragma unroll
      for (int tb = 0; tb < 8; ++tb)
#pragma unroll
        for (int r = 0; r < 4; ++r) {
          int c  = 32 * wv + 16 * ti + 4 * l16 + r;
          int cp = 16 * tb + l15;
          CovP[c * 136 + cp] = f16bits((f16)(acc[ti][tb][r] * 1e-3f));
        }
    u16* WtP = &sm.p.Wt[0][0];
    const int c = tid & 127, dh = tid >> 7;
    const float4* wp = (const float4*)(W + c * 64 + 32 * dh);
#pragma unroll
    for (int q = 0; q < 8; ++q) {
      float4 v = wp[q];
      int d0 = 32 * dh + 4 * q;
      WtP[(d0    ) * 136 + c] = f16bits((f16)v.x);
      WtP[(d0 + 1) * 136 + c] = f16bits((f16)v.y);
      WtP[(d0 + 2) * 136 + c] = f16bits((f16)v.z);
      WtP[(d0 + 3) * 136 + c] = f16bits((f16)v.w);
    }
  }
  __syncthreads();

  // mw = W^T xsum * 1e-3 (wave 0, overlaps with P MFMA on other waves)
  if (tid < 64) {
    float s = 0.f;
    for (int c = 0; c < 128; ++c)
      s = fmaf(f16tof(sm.p.Wt[tid][c]), xsL[c], s);
    mwL[tid] = s * 1.0e-3f;
  }

  // ---- P = Cov * W  (fp16 MFMA; wave wv owns rows 32wv..32wv+32) ----
  const u16* CovP = &sm.p.Cov[0][0];
  const u16* WtP  = &sm.p.Wt[0][0];
  f32x4 pAcc[2][4];
#pragma unroll
  for (int ti = 0; ti < 2; ++ti)
#pragma unroll
    for (int n = 0; n < 4; ++n) pAcc[ti][n] = zero4();
#pragma unroll
  for (int ch = 0; ch < 4; ++ch) {
    f16x8 aC[2], bw[4];
#pragma unroll
    for (int ti = 0; ti < 2; ++ti)
      aC[ti] = *(const f16x8*)&CovP[(32 * wv + 16 * ti + l15) * 136 + 8 * l16 + 32 * ch];
#pragma unroll
    for (int n = 0; n < 4; ++n)
      bw[n] = *(const f16x8*)&WtP[(16 * n + l15) * 136 + 8 * l16 + 32 * ch];
#pragma unroll
    for (int ti = 0; ti < 2; ++ti)
#pragma unroll
      for (int n = 0; n < 4; ++n)
        pAcc[ti][n] = MFMA_F16(aC[ti], bw[n], pAcc[ti][n]);
  }
  __syncthreads();   // all Cov reads done -> Pt may overlay

  // ---- Pt[d][c] = P[c][d]  (fp16, overlays Cov) ----
  {
    u16* PtP = (u16*)&sm.p.Cov[0][0];
#pragma unroll
    for (int ti = 0; ti < 2; ++ti)
#pragma unroll
      for (int n = 0; n < 4; ++n)
#pragma unroll
        for (int r = 0; r < 4; ++r) {
          int c = 32 * wv + 16 * ti + 4 * l16 + r;
          int d = 16 * n + l15;
          PtP[d * 136 + c] = f16bits((f16)pAcc[ti][n][r]);
        }
  }
  __syncthreads();

  // ---- Y = W^T P  (wave wv owns rows 16wv..16wv+16) ----
  const u16* PtP = (const u16*)&sm.p.Cov[0][0];
  f32x4 yAcc[4];
#pragma unroll
  for (int n = 0; n < 4; ++n) yAcc[n] = zero4();
#pragma unroll
  for (int ch = 0; ch < 4; ++ch) {
    f16x8 aW = *(const f16x8*)&WtP[(16 * wv + l15) * 136 + 8 * l16 + 32 * ch];
#pragma unroll
    for (int n = 0; n < 4; ++n) {
      f16x8 bP = *(const f16x8*)&PtP[(16 * n + l15) * 136 + 8 * l16 + 32 * ch];
      yAcc[n] = MFMA_F16(aW, bP, yAcc[n]);
    }
  }
  __syncthreads();   // Wt/Pt dead -> Chebyshev planes may overlay

  // ================= phase C: M init + Chebyshev matrix-log (bf16 3-term) =================
  const float CC = 1.125f;
  const float IH = 1.0f / 0.875f;
  const float uu = 0.875f / 1.125f;
  const float rho = (sqrtf(1.0f - uu * uu) - 1.0f) / uu;   // ~ -0.47759
  const float a0c = logf(CC / (1.0f + rho * rho));
  const float a1c = -2.0f * rho;

  f32x4 zz[4], tp[4], tcu[4];
  {
    u32* MHw = (u32*)&sm.c.MH[0][0];
    u32* MLw = (u32*)&sm.c.ML[0][0];
#pragma unroll
    for (int n = 0; n < 4; ++n)
#pragma unroll
      for (int r = 0; r < 4; ++r) {
        int i = 16 * wv + 4 * l16 + r, j = 16 * n + l15;
        float y = yAcc[n][r] - mwL[i] * mwL[j];
        float m = (y - ((i == j) ? CC : 0.f)) * IH;
        float e = (i == j) ? 1.f : 0.f;
        tp[n][r] = e;
        tcu[n][r] = m;
        zz[n][r] = a0c * e + a1c * m;
        writePair(MHw, MLw, i * 36 + (j >> 1), m, lane);
      }
  }
  __syncthreads();

  bf16x8 aMh[2], aMl[2];
#pragma unroll
  for (int ch = 0; ch < 2; ++ch) {
    aMh[ch] = *(const bf16x8*)&sm.c.MH[16 * wv + l15][8 * l16 + 32 * ch];
    aMl[ch] = *(const bf16x8*)&sm.c.ML[16 * wv + l15][8 * l16 + 32 * ch];
  }

  float rhok = rho;
  for (int k = 2; k <= NDEG; ++k) {
    const u16 (*srcH)[72] = (k == 2) ? sm.c.MH : sm.c.TbH[(k - 1) & 1];
    const u16 (*srcL)[72] = (k == 2) ? sm.c.ML : sm.c.TbL[(k - 1) & 1];
    f32x4 p[4];
#pragma unroll
    for (int n = 0; n < 4; ++n) p[n] = zero4();
#pragma unroll
    for (int ch = 0; ch < 2; ++ch) {
#pragma unroll
      for (int n = 0; n < 4; ++n) {
        bf16x8 bh = *(const bf16x8*)&srcH[16 * n + l15][8 * l16 + 32 * ch];
        bf16x8 bl = *(const bf16x8*)&srcL[16 * n + l15][8 * l16 + 32 * ch];
        p[n] = MFMA_BF16(aMh[ch], bh, p[n]);
        p[n] = MFMA_BF16(aMh[ch], bl, p[n]);
        p[n] = MFMA_BF16(aMl[ch], bh, p[n]);
      }
    }
    rhok *= rho;
    const float ak = (-2.0f / (float)k) * rhok;
    u32* dH = (u32*)&sm.c.TbH[k & 1][0][0];
    u32* dL = (u32*)&sm.c.TbL[k & 1][0][0];
#pragma unroll
    for (int n = 0; n < 4; ++n) {
      f32x4 tn;
#pragma unroll
      for (int r = 0; r < 4; ++r) {
        tn[r] = 2.f * p[n][r] - tp[n][r];
        zz[n][r] = fmaf(ak, tn[r], zz[n][r]);
      }
      tp[n] = tcu[n];
      tcu[n] = tn;
      if (k < NDEG) {
#pragma unroll
        for (int r = 0; r < 4; ++r) {
          int row = 16 * wv + 4 * l16 + r, col = 16 * n + l15;
          writePair(dH, dL, row * 36 + (col >> 1), tn[r], lane);
        }
      }
    }
    if (k < NDEG) __syncthreads();
  }

  // ================= classifier =================
  float po[4] = {0.f, 0.f, 0.f, 0.f};
#pragma unroll
  for (int n = 0; n < 4; ++n)
#pragma unroll
    for (int r = 0; r < 4; ++r) {
      int i = 16 * wv + 4 * l16 + r, j = 16 * n + l15;
      const float zv = zz[n][r];
      const int base = i * 64 + j;
#pragma unroll
      for (int o = 0; o < 4; ++o)
        po[o] = fmaf(zv, lin_w[o * 4096 + base], po[o]);
    }
#pragma unroll
  for (int o = 0; o < 4; ++o) redL[tid][o] = po[o];
  __syncthreads();
  if (tid < 64) {
    const int g = tid >> 4, li = tid & 15;
    float s = 0.f;
#pragma unroll
    for (int q = 0; q < 16; ++q) s += redL[li + 16 * q][g];
#pragma unroll
    for (int d = 8; d >= 1; d >>= 1) s += __shfl_down(s, d);
    if (li == 0) out[b * 4 + g] = s + lin_b[g];
  }
}

extern "C" void kernel_launch(void* const* d_in, const int* in_sizes, int n_in,
                              void* d_out, int out_size, void* d_ws, size_t ws_size,
                              hipStream_t stream) {
  const float* X     = (const float*)d_in[0];
  const float* W     = (const float*)d_in[1];
  const float* lin_w = (const float*)d_in[2];
  const float* lin_b = (const float*)d_in[3];
  float* out = (float*)d_out;
  spdnet_fused2_kernel<<<512, 256, 0, stream>>>(X, W, lin_w, lin_b, out);
}